// Round 12
// baseline (157.057 us; speedup 1.0000x reference)
//
#include <hip/hip_runtime.h>
#include <cstdint>

#define B_ 16
#define N_ 2048
#define D_ 256
#define EPS_ 1e-9f

#define AS1 __attribute__((address_space(1)))
#define AS3 __attribute__((address_space(3)))

typedef float f4 __attribute__((ext_vector_type(4)));
typedef __attribute__((ext_vector_type(8))) short short8;

__device__ inline unsigned short f2bf(float x){
  unsigned int u = __float_as_uint(x);
  u = (u + 0x7fffu + ((u >> 16) & 1u)) >> 16;
  return (unsigned short)u;
}
__device__ inline float bf2f(unsigned short u){
  return __uint_as_float(((unsigned int)u) << 16);
}

__device__ float blockReduceSum(float x, float* red){
  int tid = threadIdx.x;
  red[tid] = x; __syncthreads();
  #pragma unroll
  for (int off = 128; off > 0; off >>= 1){
    if (tid < off) red[tid] += red[tid + off];
    __syncthreads();
  }
  float r = red[0]; __syncthreads();
  return r;
}

// fp32 norm + bf16 conversion; 4 rows per wave. grid.y = src select. + state init.
__global__ __launch_bounds__(256) void prep_kernel(
    const float* __restrict__ preds, const float* __restrict__ labels,
    unsigned short* __restrict__ pabf, unsigned short* __restrict__ pbbf,
    float* __restrict__ pn, float* __restrict__ ln,
    float* __restrict__ cost, float* __restrict__ currency,
    int* __restrict__ dmin, float* __restrict__ PL,
    float* __restrict__ scal, float* __restrict__ out){
  int s = blockIdx.y;
  int tid = threadIdx.x;
  if (s == 0){
    int i = blockIdx.x * 256 + tid;
    if (i < B_ * N_){ cost[i] = 1.f; currency[i] = 1.f; }
    if (i < 2 * B_ * D_) PL[i] = 0.f;
    if (i < B_ * 4) scal[i] = 0.f;
    if (i < B_) dmin[i] = 0x7f7fffff;  // FLT_MAX bits
    if (i == 0) out[0] = 0.f;
  }
  const float* src = s ? labels : preds;
  unsigned short* dst = s ? pbbf : pabf;
  float* norms = s ? ln : pn;
  int wid = (blockIdx.x * 256 + tid) >> 6;   // 0..8191
  int lane = tid & 63;
  size_t row0 = (size_t)wid * 4;
  float4 v[4];
  #pragma unroll
  for (int q = 0; q < 4; q++)
    v[q] = ((const float4*)(src + (row0 + q) * D_))[lane];
  #pragma unroll
  for (int q = 0; q < 4; q++){
    float sum = v[q].x*v[q].x + v[q].y*v[q].y + v[q].z*v[q].z + v[q].w*v[q].w;
    #pragma unroll
    for (int off = 32; off >= 1; off >>= 1) sum += __shfl_xor(sum, off);
    if (lane == 0) norms[row0 + q] = sum;
    ushort4 o; o.x = f2bf(v[q].x); o.y = f2bf(v[q].y); o.z = f2bf(v[q].z); o.w = f2bf(v[q].w);
    ((ushort4*)(dst + (row0 + q) * D_))[lane] = o;
  }
}

// d[b][n][m] = pn[n] + ln[m] - 2*dot via bf16 MFMA; NO stores — only per-batch min.
// ROUND 12: occupancy-first. Tile 256x128, BK=32, 512 threads, wave tile 64x64
// (acc = 64 VGPRs) -> __launch_bounds__(512,4) -> 4 waves/SIMD, 2 blocks/CU
// (LDS 48 KB dbuf). Rounds 5/7/11 showed the 2-waves/SIMD configs are
// dependency-stall-bound (~30% on every pipe); this doubles resident waves.
// PAIRED-ROW LDS: BK=32 gives 64-B source rows; each 128-B LDS row q packs
// source rows {2q, 2q+1}, chunk c' = c ^ (q&7) (XOR applied on the GLOBAL
// address side; LDS dest stays wave-uniform base + lane*16). ds_read af/bf:
// q = r>>1, c = (r&1)*4 + quad — 8 lanes sharing a chunk-slot span 8 distinct
// q&7 -> conflict-free (round-4-proven structure, re-derived for 64-B rows).
// Batch->XCD pinning kept (FETCH == input size, round 8).
__global__ __launch_bounds__(512, 4) void gemm_minmax(
    const unsigned short* __restrict__ pa, const unsigned short* __restrict__ pbm,
    const float* __restrict__ pn, const float* __restrict__ ln,
    int* __restrict__ dmin)
{
  int lid = blockIdx.x;              // 0..2047, round-robin over 8 XCDs
  int xcd = lid & 7, sq = lid >> 3;  // sq 0..255 per XCD
  int b = 2 * xcd + (sq >> 7);       // 2 batches per XCD
  int t = sq & 127;
  int tm = (t & 7) * 256;            // tm fastest: 8 consecutive blocks share tn
  int tn = (t >> 3) * 128;
  const unsigned short* A  = pa  + (size_t)b * N_ * D_;
  const unsigned short* Bm = pbm + (size_t)b * N_ * D_;
  __shared__ __align__(16) unsigned short As[2][256 * 32];
  __shared__ __align__(16) unsigned short Bs[2][128 * 32];
  __shared__ float minred[8];
  int tid = threadIdx.x, lane = tid & 63, w = tid >> 6;
  int wm = (w >> 1) * 64, wn = (w & 1) * 64;
  int quad = lane >> 4, l15 = lane & 15;
  int l8 = lane >> 3, c7 = lane & 7;

  f4 acc[4][4];
  #pragma unroll
  for (int i = 0; i < 4; i++)
    #pragma unroll
    for (int j = 0; j < 4; j++) acc[i][j] = (f4)0.f;

  // stage ki into buffer bufI: As = 2 wave-parts, Bs = 1 wave-part
  auto stage = [&](int ki, int bufI){
    int kt = ki * 32;
    #pragma unroll
    for (int p = 0; p < 2; p++){
      int Q0 = p * 64 + w * 8;
      int q = Q0 + l8;
      int c = c7 ^ (q & 7);
      int sr = 2 * q + (c >> 2);
      int kc = c & 3;
      __builtin_amdgcn_global_load_lds(
          (const AS1 unsigned int*)(const void*)&A[(size_t)(tm + sr) * D_ + kt + kc * 8],
          (AS3 unsigned int*)(void*)&As[bufI][Q0 * 64], 16, 0, 0);
    }
    {
      int Q0 = w * 8;
      int q = Q0 + l8;
      int c = c7 ^ (q & 7);
      int sr = 2 * q + (c >> 2);
      int kc = c & 3;
      __builtin_amdgcn_global_load_lds(
          (const AS1 unsigned int*)(const void*)&Bm[(size_t)(tn + sr) * D_ + kt + kc * 8],
          (AS3 unsigned int*)(void*)&Bs[bufI][Q0 * 64], 16, 0, 0);
    }
  };

  stage(0, 0);
  int buf = 0;
  for (int ki = 0; ki < 8; ki++){
    __syncthreads();   // drains buf's loads (issued one compute-phase ago)
    if (ki < 7) stage(ki + 1, buf ^ 1);
    short8 af[4], bf[4];
    #pragma unroll
    for (int i = 0; i < 4; i++){
      int ra = wm + i * 16 + l15;
      int q = ra >> 1;
      int c = (ra & 1) * 4 + quad;
      af[i] = *(const short8*)(&As[buf][q * 64 + ((c ^ (q & 7)) * 8)]);
    }
    #pragma unroll
    for (int jj = 0; jj < 4; jj++){
      int rb = wn + jj * 16 + l15;
      int q = rb >> 1;
      int c = (rb & 1) * 4 + quad;
      bf[jj] = *(const short8*)(&Bs[buf][q * 64 + ((c ^ (q & 7)) * 8)]);
    }
    #pragma unroll
    for (int i = 0; i < 4; i++)
      #pragma unroll
      for (int jj = 0; jj < 4; jj++)
        acc[i][jj] = __builtin_amdgcn_mfma_f32_16x16x32_bf16(af[i], bf[jj], acc[i][jj], 0, 0, 0);
    buf ^= 1;
  }

  // epilogue: load pn/ln post-loop (pre-loop preload = round-9 spill bomb).
  // C/D layout col = lane&15, row = quad*4 + reg.
  float4 pnr[4];
  float lnr[4];
  #pragma unroll
  for (int i = 0; i < 4; i++)
    pnr[i] = *(const float4*)&pn[(size_t)b * N_ + tm + wm + i * 16 + quad * 4];
  #pragma unroll
  for (int jj = 0; jj < 4; jj++)
    lnr[jj] = ln[(size_t)b * N_ + tn + wn + jj * 16 + l15];

  float mind = 3.4e38f;
  #pragma unroll
  for (int i = 0; i < 4; i++){
    float pv[4] = {pnr[i].x, pnr[i].y, pnr[i].z, pnr[i].w};
    #pragma unroll
    for (int jj = 0; jj < 4; jj++){
      #pragma unroll
      for (int reg = 0; reg < 4; reg++){
        float v = pv[reg] + lnr[jj] - 2.f * acc[i][jj][reg];
        mind = fminf(mind, v);
      }
    }
  }
  #pragma unroll
  for (int off = 32; off >= 1; off >>= 1) mind = fminf(mind, __shfl_xor(mind, off));
  if (lane == 0) minred[w] = mind;
  __syncthreads();
  if (tid == 0){
    float m = minred[0];
    #pragma unroll
    for (int q = 1; q < 8; q++) m = fminf(m, minred[q]);
    atomicMin(&dmin[b], __float_as_int(fmaxf(m, 0.f)));
  }
}

// Exact fallback for the 6 negative exp-factors (skipped when provably
// negligible: B*N^2*dmax*e^{ef*dmin}/EPS < 1e-3 iff ef*(dmin-8) < -55),
// followed by the ef=0 closed-form scalars.
__global__ __launch_bounds__(256) void fb_all(
    const unsigned short* __restrict__ pabf, const unsigned short* __restrict__ pbbf,
    const float* __restrict__ pn, const float* __restrict__ ln,
    float* __restrict__ cost, float* __restrict__ currency,
    const int* __restrict__ dmin, float* __restrict__ out,
    float* __restrict__ alpha, float* __restrict__ v, float* __restrict__ scal)
{
  const float EF[6] = {-256.f, -64.f, -16.f, -4.f, -1.f, -0.25f};
  int b = blockIdx.x, tid = threadIdx.x;
  float dm = __int_as_float(dmin[b]);
  __shared__ float red[256];
  __shared__ float alpha_l[N_];
  __shared__ float prow[D_];
  const unsigned short* A  = pabf + (size_t)b * N_ * D_;
  const unsigned short* Bm = pbbf + (size_t)b * N_ * D_;
  const float* pnb = pn + (size_t)b * N_;
  const float* lnb = ln + (size_t)b * N_;
  float* costb = cost + (size_t)b * N_;
  float* curb  = currency + (size_t)b * N_;
  for (int it = 0; it < 6; it++){
    float ef = EF[it];
    if (ef * (dm - 8.f) < -55.f) continue;   // provably negligible contribution
    // ---- exact slow path (not expected to execute for this input) ----
    float cost_c[8], colsum_c[8], bw_c[8], costnew_c[8];
    #pragma unroll
    for (int j = 0; j < 8; j++){ cost_c[j] = costb[j*256+tid]; colsum_c[j] = 0.f; }
    for (int r = 0; r < N_; r++){
      prow[tid] = bf2f(A[(size_t)r * D_ + tid]);
      __syncthreads();
      float s_c[8], rs = 0.f;
      for (int j = 0; j < 8; j++){
        int m = j*256+tid; float dot = 0.f;
        for (int k = 0; k < D_; k++) dot += prow[k] * bf2f(Bm[(size_t)m * D_ + k]);
        float d = pnb[r] + lnb[m] - 2.f*dot;
        float s = __expf(ef * d) * cost_c[j];
        s_c[j] = s; rs += s;
      }
      float tot = blockReduceSum(rs, red);
      float a = curb[r] / (tot + EPS_);
      if (tid == 0) alpha_l[r] = a;
      #pragma unroll
      for (int j = 0; j < 8; j++) colsum_c[j] += s_c[j] * a;
      __syncthreads();
    }
    #pragma unroll
    for (int j = 0; j < 8; j++){
      float cs = colsum_c[j];
      float bw = fminf(cost_c[j] / (cs + EPS_), 1.f);
      bw_c[j] = bw; costnew_c[j] = fmaxf(cost_c[j] - bw*cs, 0.f);
    }
    float contrib = 0.f;
    for (int r = 0; r < N_; r++){
      prow[tid] = bf2f(A[(size_t)r * D_ + tid]);
      __syncthreads();
      float a = alpha_l[r], rbs = 0.f;
      for (int j = 0; j < 8; j++){
        int m = j*256+tid; float dot = 0.f;
        for (int k = 0; k < D_; k++) dot += prow[k] * bf2f(Bm[(size_t)m * D_ + k]);
        float d = pnb[r] + lnb[m] - 2.f*dot;
        float bid = __expf(ef * d) * cost_c[j] * a * bw_c[j];
        rbs += bid; contrib += bid * d;
      }
      float tot = blockReduceSum(rbs, red);
      if (tid == 0) curb[r] = fmaxf(curb[r] - tot, 0.f);
      __syncthreads();
    }
    #pragma unroll
    for (int j = 0; j < 8; j++) costb[j*256+tid] = costnew_c[j];
    float ctot = blockReduceSum(contrib, red);
    if (tid == 0) atomicAdd(out, ctot);
    __syncthreads();
  }
  // ---- fused ef=0 closed-form scalars: exp(0*d)=1 exactly, so
  // sum(bids*d) = Spn*Sv + Sa*Sln - 2*(sum alpha*p).(sum v*l). ----
  float* ab = alpha + (size_t)b * N_;
  float* vb = v + (size_t)b * N_;
  float s = 0.f;
  #pragma unroll
  for (int j = 0; j < 8; j++) s += costb[j*256+tid];
  float Sc = blockReduceSum(s, red);
  float sa = 0.f, spn = 0.f;
  #pragma unroll
  for (int j = 0; j < 8; j++){
    int i = j*256+tid;
    float a = curb[i] / (Sc + EPS_);
    ab[i] = a; sa += a; spn += a * pnb[i];
  }
  float Sa  = blockReduceSum(sa, red);
  float Spn = blockReduceSum(spn, red);
  float sv = 0.f, sln = 0.f;
  #pragma unroll
  for (int j = 0; j < 8; j++){
    int i = j*256+tid;
    float c = costb[j*256+tid];
    float bw = fminf(c / (c * Sa + EPS_), 1.f);
    float vv = c * bw;
    vb[i] = vv; sv += vv; sln += vv * lnb[i];
  }
  float Sv  = blockReduceSum(sv, red);
  float Sln = blockReduceSum(sln, red);
  if (tid == 0){
    scal[b*4+0] = Sa; scal[b*4+1] = Sv; scal[b*4+2] = Spn; scal[b*4+3] = Sln;
  }
}

// P_b = sum_r alpha_r * preds[b][r][:], L_b = sum_m v_m * labels[b][m][:]
__global__ __launch_bounds__(256) void cf_wsum(
    const unsigned short* __restrict__ pabf, const unsigned short* __restrict__ pbbf,
    const float* __restrict__ alpha, const float* __restrict__ v,
    float* __restrict__ PL)
{
  int chunk = blockIdx.x, src = blockIdx.y, b = blockIdx.z, tid = threadIdx.x;
  int g = tid >> 6, c4 = (tid & 63) * 4;
  const unsigned short* X = (src ? pbbf : pabf) + ((size_t)b * N_ + chunk * 64) * D_;
  const float* wv = (src ? v : alpha) + (size_t)b * N_ + chunk * 64;
  __shared__ float wl[64];
  __shared__ float part[4][D_];
  if (tid < 64) wl[tid] = wv[tid];
  __syncthreads();
  f4 acc = (f4)0.f;
  for (int r = g * 16; r < g * 16 + 16; r++){
    uint2 pk = *(const uint2*)&X[(size_t)r * D_ + c4];
    float wr = wl[r];
    acc[0] = fmaf(wr, __uint_as_float(pk.x << 16), acc[0]);
    acc[1] = fmaf(wr, __uint_as_float(pk.x & 0xffff0000u), acc[1]);
    acc[2] = fmaf(wr, __uint_as_float(pk.y << 16), acc[2]);
    acc[3] = fmaf(wr, __uint_as_float(pk.y & 0xffff0000u), acc[3]);
  }
  #pragma unroll
  for (int q = 0; q < 4; q++) part[g][c4 + q] = acc[q];
  __syncthreads();
  float s = part[0][tid] + part[1][tid] + part[2][tid] + part[3][tid];
  atomicAdd(&PL[((size_t)src * B_ + b) * D_ + tid], s);
}

__global__ __launch_bounds__(256) void cf_final(
    const float* __restrict__ PL, const float* __restrict__ scal,
    float* __restrict__ out)
{
  int b = blockIdx.x, tid = threadIdx.x;
  __shared__ float red[256];
  float p = PL[(size_t)b * D_ + tid] * PL[((size_t)B_ + b) * D_ + tid];
  float dot = blockReduceSum(p, red);
  if (tid == 0){
    float Sa = scal[b*4+0], Sv = scal[b*4+1], Spn = scal[b*4+2], Sln = scal[b*4+3];
    atomicAdd(out, Spn * Sv + Sa * Sln - 2.f * dot);
  }
}

extern "C" void kernel_launch(void* const* d_in, const int* in_sizes, int n_in,
                              void* d_out, int out_size, void* d_ws, size_t ws_size,
                              hipStream_t stream)
{
  const float* preds  = (const float*)d_in[0];
  const float* labels = (const float*)d_in[1];
  float* out = (float*)d_out;
  char* ws = (char*)d_ws;
  const size_t BN = (size_t)B_ * N_;
  size_t off = 0;
  float* cost     = (float*)(ws + off); off += BN * 4;
  float* currency = (float*)(ws + off); off += BN * 4;
  float* alpha    = (float*)(ws + off); off += BN * 4;
  float* v        = (float*)(ws + off); off += BN * 4;
  float* pn       = (float*)(ws + off); off += BN * 4;
  float* ln       = (float*)(ws + off); off += BN * 4;
  int*   dmin     = (int*)(ws + off);   off += 256;
  float* scal     = (float*)(ws + off); off += 256;
  float* PL       = (float*)(ws + off); off += (size_t)2 * B_ * D_ * 4;
  unsigned short* pabf = (unsigned short*)(ws + off); off += BN * D_ * 2;
  unsigned short* pbbf = (unsigned short*)(ws + off); off += BN * D_ * 2;

  prep_kernel<<<dim3((unsigned)(BN / 16), 2), 256, 0, stream>>>(
      preds, labels, pabf, pbbf, pn, ln, cost, currency, dmin, PL, scal, out);
  gemm_minmax<<<dim3(2048), 512, 0, stream>>>(pabf, pbbf, pn, ln, dmin);
  fb_all<<<dim3(B_), 256, 0, stream>>>(pabf, pbbf, pn, ln, cost, currency, dmin, out,
                                       alpha, v, scal);
  cf_wsum<<<dim3(32, 2, B_), 256, 0, stream>>>(pabf, pbbf, alpha, v, PL);
  cf_final<<<dim3(B_), 256, 0, stream>>>(PL, scal, out);
}

// Round 13
// 148.775 us; speedup vs baseline: 1.0557x; 1.0557x over previous
//
#include <hip/hip_runtime.h>
#include <cstdint>

#define B_ 16
#define N_ 2048
#define D_ 256
#define EPS_ 1e-9f

#define AS1 __attribute__((address_space(1)))
#define AS3 __attribute__((address_space(3)))

typedef float f4 __attribute__((ext_vector_type(4)));
typedef __attribute__((ext_vector_type(8))) short short8;

__device__ inline unsigned short f2bf(float x){
  unsigned int u = __float_as_uint(x);
  u = (u + 0x7fffu + ((u >> 16) & 1u)) >> 16;
  return (unsigned short)u;
}
__device__ inline float bf2f(unsigned short u){
  return __uint_as_float(((unsigned int)u) << 16);
}

__device__ float blockReduceSum(float x, float* red){
  int tid = threadIdx.x;
  red[tid] = x; __syncthreads();
  #pragma unroll
  for (int off = 128; off > 0; off >>= 1){
    if (tid < off) red[tid] += red[tid + off];
    __syncthreads();
  }
  float r = red[0]; __syncthreads();
  return r;
}

// fp32 norm + bf16 conversion; 4 rows/wave, 16 rows/block (one batch per block).
// Emits RACE-FREE per-block partials: Ppart[src][blk][256] = col-sums of the
// block's 16 rows, npart[src][blk] = norm-sum — consumed by finalize's fast
// path (exact when all negative iterations are certified skippable).
__global__ __launch_bounds__(256) void prep_kernel(
    const float* __restrict__ preds, const float* __restrict__ labels,
    unsigned short* __restrict__ pabf, unsigned short* __restrict__ pbbf,
    float* __restrict__ pn, float* __restrict__ ln,
    float* __restrict__ cost, float* __restrict__ currency,
    int* __restrict__ dmin, float* __restrict__ Ppart,
    float* __restrict__ npart){
  int s = blockIdx.y;
  int tid = threadIdx.x;
  if (s == 0){
    int i = blockIdx.x * 256 + tid;
    if (i < B_ * N_){ cost[i] = 1.f; currency[i] = 1.f; }
    if (i < B_) dmin[i] = 0x7f7fffff;  // FLT_MAX bits
  }
  const float* src = s ? labels : preds;
  unsigned short* dst = s ? pbbf : pabf;
  float* norms = s ? ln : pn;
  int w = tid >> 6, lane = tid & 63;
  size_t row0 = (size_t)blockIdx.x * 16 + (size_t)w * 4;
  float4 v[4];
  #pragma unroll
  for (int q = 0; q < 4; q++)
    v[q] = ((const float4*)(src + (row0 + q) * D_))[lane];
  __shared__ f4 part[4][64];
  __shared__ float nred[4];
  f4 s4;
  s4[0] = v[0].x + v[1].x + v[2].x + v[3].x;
  s4[1] = v[0].y + v[1].y + v[2].y + v[3].y;
  s4[2] = v[0].z + v[1].z + v[2].z + v[3].z;
  s4[3] = v[0].w + v[1].w + v[2].w + v[3].w;
  float nsum = 0.f;
  #pragma unroll
  for (int q = 0; q < 4; q++){
    float sum = v[q].x*v[q].x + v[q].y*v[q].y + v[q].z*v[q].z + v[q].w*v[q].w;
    #pragma unroll
    for (int off = 32; off >= 1; off >>= 1) sum += __shfl_xor(sum, off);
    if (lane == 0){ norms[row0 + q] = sum; nsum += sum; }
    ushort4 o; o.x = f2bf(v[q].x); o.y = f2bf(v[q].y); o.z = f2bf(v[q].z); o.w = f2bf(v[q].w);
    ((ushort4*)(dst + (row0 + q) * D_))[lane] = o;
  }
  part[w][lane] = s4;
  if (lane == 0) nred[w] = nsum;
  __syncthreads();
  if (tid < 64){
    f4 t = part[0][tid];
    #pragma unroll
    for (int q = 1; q < 4; q++){
      t[0] += part[q][tid][0]; t[1] += part[q][tid][1];
      t[2] += part[q][tid][2]; t[3] += part[q][tid][3];
    }
    *(f4*)(Ppart + ((size_t)s * 2048 + blockIdx.x) * 256 + tid * 4) = t;
  }
  if (tid == 0)
    npart[s * 2048 + blockIdx.x] = nred[0] + nred[1] + nred[2] + nred[3];
}

// d[b][n][m] = pn[n] + ln[m] - 2*dot via bf16 MFMA; NO stores — only per-batch min.
// ROUND-10 CHAMPION VERBATIM (43 us, 800 TF ~ the m97-structure source-level
// plateau): 256x256 tile, 512 threads, wave tile 128x64, BK=64, dbuf 128 KB,
// 128-B LDS rows + XOR r&7 (0 conflicts), batch->XCD pinning (FETCH == input
// size), pn/ln loaded AFTER the K-loop (pre-loop preload spills at 256-reg cap).
__global__ __launch_bounds__(512, 2) void gemm_minmax(
    const unsigned short* __restrict__ pa, const unsigned short* __restrict__ pbm,
    const float* __restrict__ pn, const float* __restrict__ ln,
    int* __restrict__ dmin)
{
  int lid = blockIdx.x;              // 1024 blocks, round-robin over 8 XCDs
  int l = lid >> 3;                  // 0..127 sequential per XCD
  int b = 2 * (lid & 7) + (l >> 6);  // 2 batches per XCD
  int t = l & 63;
  int tm = (t & 7) * 256, tn = (t >> 3) * 256;  // tm fastest: B-slice stays L2-hot
  const unsigned short* A  = pa  + (size_t)b * N_ * D_;
  const unsigned short* Bm = pbm + (size_t)b * N_ * D_;
  __shared__ __align__(16) unsigned short As[2][256 * 64];
  __shared__ __align__(16) unsigned short Bs[2][256 * 64];
  __shared__ float minred[8];
  int tid = threadIdx.x, lane = tid & 63, w = tid >> 6;
  int wm = (w >> 2) * 128, wn = (w & 3) * 64;
  int quad = lane >> 4, l15 = lane & 15;

  f4 acc[8][4];
  #pragma unroll
  for (int i = 0; i < 8; i++)
    #pragma unroll
    for (int j = 0; j < 4; j++) acc[i][j] = (f4)0.f;

  int lr = lane >> 3, ch = lane & 7;
  int gch = (ch ^ lr) * 8;           // XOR swizzle on the GLOBAL side (r&7 == lr)

  #pragma unroll
  for (int p = 0; p < 4; p++){
    int R = p * 64 + w * 8;
    int r = R + lr;
    __builtin_amdgcn_global_load_lds(
        (const AS1 unsigned int*)(const void*)&A[(size_t)(tm + r) * D_ + gch],
        (AS3 unsigned int*)(void*)&As[0][R * 64], 16, 0, 0);
    __builtin_amdgcn_global_load_lds(
        (const AS1 unsigned int*)(const void*)&Bm[(size_t)(tn + r) * D_ + gch],
        (AS3 unsigned int*)(void*)&Bs[0][R * 64], 16, 0, 0);
  }

  int buf = 0;
  for (int ki = 0; ki < 4; ki++){
    __syncthreads();   // drains buf's loads (issued one compute-phase ago)
    if (ki < 3){
      int kt = (ki + 1) * 64;
      #pragma unroll
      for (int p = 0; p < 4; p++){
        int R = p * 64 + w * 8;
        int r = R + lr;
        __builtin_amdgcn_global_load_lds(
            (const AS1 unsigned int*)(const void*)&A[(size_t)(tm + r) * D_ + kt + gch],
            (AS3 unsigned int*)(void*)&As[buf ^ 1][R * 64], 16, 0, 0);
        __builtin_amdgcn_global_load_lds(
            (const AS1 unsigned int*)(const void*)&Bm[(size_t)(tn + r) * D_ + kt + gch],
            (AS3 unsigned int*)(void*)&Bs[buf ^ 1][R * 64], 16, 0, 0);
      }
    }
    #pragma unroll
    for (int ks = 0; ks < 2; ks++){
      short8 af[8], bf[4];
      int j = ks * 4 + quad;
      #pragma unroll
      for (int i = 0; i < 8; i++){
        int ra = wm + i * 16 + l15;
        af[i] = *(const short8*)(&As[buf][ra * 64 + ((j ^ (ra & 7)) * 8)]);
      }
      #pragma unroll
      for (int jj = 0; jj < 4; jj++){
        int rb = wn + jj * 16 + l15;
        bf[jj] = *(const short8*)(&Bs[buf][rb * 64 + ((j ^ (rb & 7)) * 8)]);
      }
      #pragma unroll
      for (int i = 0; i < 8; i++)
        #pragma unroll
        for (int jj = 0; jj < 4; jj++)
          acc[i][jj] = __builtin_amdgcn_mfma_f32_16x16x32_bf16(af[i], bf[jj], acc[i][jj], 0, 0, 0);
    }
    buf ^= 1;
  }

  float4 pnr[8];
  float lnr[4];
  #pragma unroll
  for (int i = 0; i < 8; i++)
    pnr[i] = *(const float4*)&pn[(size_t)b * N_ + tm + wm + i * 16 + quad * 4];
  #pragma unroll
  for (int jj = 0; jj < 4; jj++)
    lnr[jj] = ln[(size_t)b * N_ + tn + wn + jj * 16 + l15];

  float mind = 3.4e38f;
  #pragma unroll
  for (int i = 0; i < 8; i++){
    float pv[4] = {pnr[i].x, pnr[i].y, pnr[i].z, pnr[i].w};
    #pragma unroll
    for (int jj = 0; jj < 4; jj++){
      #pragma unroll
      for (int reg = 0; reg < 4; reg++){
        float v = pv[reg] + lnr[jj] - 2.f * acc[i][jj][reg];
        mind = fminf(mind, v);
      }
    }
  }
  #pragma unroll
  for (int off = 32; off >= 1; off >>= 1) mind = fminf(mind, __shfl_xor(mind, off));
  if (lane == 0) minred[w] = mind;
  __syncthreads();
  if (tid == 0){
    float m = minred[0];
    #pragma unroll
    for (int q = 1; q < 8; q++) m = fminf(m, minred[q]);
    atomicMin(&dmin[b], __float_as_int(fmaxf(m, 0.f)));
  }
}

// Exact fallback for the 6 negative exp-factors only (skipped when provably
// negligible: B*N^2*dmax*e^{ef*dmin}/EPS < 1e-3 iff ef*(dmin-8) < -55).
// The ef=0 term is handled entirely by finalize.
__global__ __launch_bounds__(256) void fb_all(
    const unsigned short* __restrict__ pabf, const unsigned short* __restrict__ pbbf,
    const float* __restrict__ pn, const float* __restrict__ ln,
    float* __restrict__ cost, float* __restrict__ currency,
    const int* __restrict__ dmin, float* __restrict__ out)
{
  const float EF[6] = {-256.f, -64.f, -16.f, -4.f, -1.f, -0.25f};
  int b = blockIdx.x, tid = threadIdx.x;
  float dm = __int_as_float(dmin[b]);
  __shared__ float red[256];
  __shared__ float alpha_l[N_];
  __shared__ float prow[D_];
  const unsigned short* A  = pabf + (size_t)b * N_ * D_;
  const unsigned short* Bm = pbbf + (size_t)b * N_ * D_;
  const float* pnb = pn + (size_t)b * N_;
  const float* lnb = ln + (size_t)b * N_;
  float* costb = cost + (size_t)b * N_;
  float* curb  = currency + (size_t)b * N_;
  for (int it = 0; it < 6; it++){
    float ef = EF[it];
    if (ef * (dm - 8.f) < -55.f) continue;   // provably negligible contribution
    // ---- exact slow path (not expected to execute for this input) ----
    float cost_c[8], colsum_c[8], bw_c[8], costnew_c[8];
    #pragma unroll
    for (int j = 0; j < 8; j++){ cost_c[j] = costb[j*256+tid]; colsum_c[j] = 0.f; }
    for (int r = 0; r < N_; r++){
      prow[tid] = bf2f(A[(size_t)r * D_ + tid]);
      __syncthreads();
      float s_c[8], rs = 0.f;
      for (int j = 0; j < 8; j++){
        int m = j*256+tid; float dot = 0.f;
        for (int k = 0; k < D_; k++) dot += prow[k] * bf2f(Bm[(size_t)m * D_ + k]);
        float d = pnb[r] + lnb[m] - 2.f*dot;
        float s = __expf(ef * d) * cost_c[j];
        s_c[j] = s; rs += s;
      }
      float tot = blockReduceSum(rs, red);
      float a = curb[r] / (tot + EPS_);
      if (tid == 0) alpha_l[r] = a;
      #pragma unroll
      for (int j = 0; j < 8; j++) colsum_c[j] += s_c[j] * a;
      __syncthreads();
    }
    #pragma unroll
    for (int j = 0; j < 8; j++){
      float cs = colsum_c[j];
      float bw = fminf(cost_c[j] / (cs + EPS_), 1.f);
      bw_c[j] = bw; costnew_c[j] = fmaxf(cost_c[j] - bw*cs, 0.f);
    }
    float contrib = 0.f;
    for (int r = 0; r < N_; r++){
      prow[tid] = bf2f(A[(size_t)r * D_ + tid]);
      __syncthreads();
      float a = alpha_l[r], rbs = 0.f;
      for (int j = 0; j < 8; j++){
        int m = j*256+tid; float dot = 0.f;
        for (int k = 0; k < D_; k++) dot += prow[k] * bf2f(Bm[(size_t)m * D_ + k]);
        float d = pnb[r] + lnb[m] - 2.f*dot;
        float bid = __expf(ef * d) * cost_c[j] * a * bw_c[j];
        rbs += bid; contrib += bid * d;
      }
      float tot = blockReduceSum(rbs, red);
      if (tid == 0) curb[r] = fmaxf(curb[r] - tot, 0.f);
      __syncthreads();
    }
    #pragma unroll
    for (int j = 0; j < 8; j++) costb[j*256+tid] = costnew_c[j];
    float ctot = blockReduceSum(contrib, red);
    if (tid == 0) atomicAdd(out, ctot);
    __syncthreads();
  }
}

// ef=0 term. FAST PATH (all 6 negative factors certified skipped -> cost ==
// currency == 1 exactly): alpha = 1/2048 exactly (power of 2; 2048+1e-9 rounds
// to 2048 in fp32), bw = 1, so the term collapses to
//   sum|p|^2 + sum|l|^2 - (sum p).(sum l)/1024
// computed from prep's fp32 partials. SLOW PATH (dead here): exact in-block
// replication of the general closed form using the bf16 panels.
__global__ __launch_bounds__(256) void finalize(
    const unsigned short* __restrict__ pabf, const unsigned short* __restrict__ pbbf,
    const float* __restrict__ pn, const float* __restrict__ ln,
    const float* __restrict__ cost, const float* __restrict__ currency,
    const int* __restrict__ dmin, const float* __restrict__ Ppart,
    const float* __restrict__ npart, float* __restrict__ out)
{
  int b = blockIdx.x, tid = threadIdx.x;
  __shared__ float red[256];
  float dm = __int_as_float(dmin[b]);
  if (-0.25f * (dm - 8.f) < -55.f){   // same expression as fb_all's skip test
    float Pc = 0.f, Lc = 0.f;
    for (int k = 0; k < 128; k++){
      Pc += Ppart[((size_t)b * 128 + k) * 256 + tid];
      Lc += Ppart[((size_t)(2048 + b * 128 + k)) * 256 + tid];
    }
    float np = (tid < 128) ? npart[b * 128 + tid] : 0.f;
    float nl = (tid < 128) ? npart[2048 + b * 128 + tid] : 0.f;
    float Spn = blockReduceSum(np, red);
    float Sln = blockReduceSum(nl, red);
    float dot = blockReduceSum(Pc * Lc, red);
    if (tid == 0) atomicAdd(out, Spn + Sln - dot * (1.f / 1024.f));
    return;
  }
  // ---- slow exact path ----
  __shared__ float warr[N_];
  const unsigned short* A  = pabf + (size_t)b * N_ * D_;
  const unsigned short* Bm = pbbf + (size_t)b * N_ * D_;
  const float* pnb = pn + (size_t)b * N_;
  const float* lnb = ln + (size_t)b * N_;
  const float* costb = cost + (size_t)b * N_;
  const float* curb  = currency + (size_t)b * N_;
  float s = 0.f;
  #pragma unroll
  for (int j = 0; j < 8; j++) s += costb[j*256+tid];
  float Sc = blockReduceSum(s, red);
  float sa = 0.f, spn = 0.f;
  #pragma unroll
  for (int j = 0; j < 8; j++){
    int i = j*256+tid;
    float a = curb[i] / (Sc + EPS_);
    warr[i] = a; sa += a; spn += a * pnb[i];
  }
  float Sa  = blockReduceSum(sa, red);
  float Spn = blockReduceSum(spn, red);
  float Pc = 0.f;
  for (int r = 0; r < N_; r++)
    Pc += warr[r] * bf2f(A[(size_t)r * D_ + tid]);
  __syncthreads();
  float sv = 0.f, sln = 0.f;
  #pragma unroll
  for (int j = 0; j < 8; j++){
    int i = j*256+tid;
    float c = costb[i];
    float bw = fminf(c / (c * Sa + EPS_), 1.f);
    float vv = c * bw;
    warr[i] = vv; sv += vv; sln += vv * lnb[i];
  }
  float Sv  = blockReduceSum(sv, red);
  float Sln = blockReduceSum(sln, red);
  float Lc = 0.f;
  for (int m = 0; m < N_; m++)
    Lc += warr[m] * bf2f(Bm[(size_t)m * D_ + tid]);
  float dot = blockReduceSum(Pc * Lc, red);
  if (tid == 0) atomicAdd(out, Spn * Sv + Sa * Sln - 2.f * dot);
}

extern "C" void kernel_launch(void* const* d_in, const int* in_sizes, int n_in,
                              void* d_out, int out_size, void* d_ws, size_t ws_size,
                              hipStream_t stream)
{
  const float* preds  = (const float*)d_in[0];
  const float* labels = (const float*)d_in[1];
  float* out = (float*)d_out;
  char* ws = (char*)d_ws;
  const size_t BN = (size_t)B_ * N_;
  size_t off = 0;
  float* cost     = (float*)(ws + off); off += BN * 4;
  float* currency = (float*)(ws + off); off += BN * 4;
  float* pn       = (float*)(ws + off); off += BN * 4;
  float* ln       = (float*)(ws + off); off += BN * 4;
  int*   dmin     = (int*)(ws + off);   off += 256;
  float* npart    = (float*)(ws + off); off += (size_t)2 * 2048 * 4;
  float* Ppart    = (float*)(ws + off); off += (size_t)2 * 2048 * 256 * 4;
  unsigned short* pabf = (unsigned short*)(ws + off); off += BN * D_ * 2;
  unsigned short* pbbf = (unsigned short*)(ws + off); off += BN * D_ * 2;

  hipMemsetAsync(d_out, 0, 4, stream);
  prep_kernel<<<dim3((unsigned)(BN / 16), 2), 256, 0, stream>>>(
      preds, labels, pabf, pbbf, pn, ln, cost, currency, dmin, Ppart, npart);
  gemm_minmax<<<dim3(1024), 512, 0, stream>>>(pabf, pbbf, pn, ln, dmin);
  fb_all<<<dim3(B_), 256, 0, stream>>>(pabf, pbbf, pn, ln, cost, currency, dmin, out);
  finalize<<<dim3(B_), 256, 0, stream>>>(pabf, pbbf, pn, ln, cost, currency, dmin,
                                         Ppart, npart, out);
}

// Round 14
// 146.626 us; speedup vs baseline: 1.0711x; 1.0147x over previous
//
#include <hip/hip_runtime.h>
#include <cstdint>

#define B_ 16
#define N_ 2048
#define D_ 256
#define EPS_ 1e-9f

#define AS1 __attribute__((address_space(1)))
#define AS3 __attribute__((address_space(3)))

typedef float f4 __attribute__((ext_vector_type(4)));
typedef __attribute__((ext_vector_type(8))) short short8;

__device__ inline unsigned short f2bf(float x){
  unsigned int u = __float_as_uint(x);
  u = (u + 0x7fffu + ((u >> 16) & 1u)) >> 16;
  return (unsigned short)u;
}
__device__ inline float bf2f(unsigned short u){
  return __uint_as_float(((unsigned int)u) << 16);
}

__device__ float blockReduceSum(float x, float* red){
  int tid = threadIdx.x;
  red[tid] = x; __syncthreads();
  #pragma unroll
  for (int off = 128; off > 0; off >>= 1){
    if (tid < off) red[tid] += red[tid + off];
    __syncthreads();
  }
  float r = red[0]; __syncthreads();
  return r;
}

// fp32 norm + bf16 conversion; 4 rows/wave, 16 rows/block (one batch per block).
// Emits RACE-FREE per-block partials: Ppart[src][blk][256] = col-sums of the
// block's 16 rows, npart[src][blk] = norm-sum — consumed by tail's fast path.
// Also inits cost/currency/dmin/out (no separate memset dispatch).
__global__ __launch_bounds__(256) void prep_kernel(
    const float* __restrict__ preds, const float* __restrict__ labels,
    unsigned short* __restrict__ pabf, unsigned short* __restrict__ pbbf,
    float* __restrict__ pn, float* __restrict__ ln,
    float* __restrict__ cost, float* __restrict__ currency,
    int* __restrict__ dmin, float* __restrict__ Ppart,
    float* __restrict__ npart, float* __restrict__ out){
  int s = blockIdx.y;
  int tid = threadIdx.x;
  if (s == 0){
    int i = blockIdx.x * 256 + tid;
    if (i < B_ * N_){ cost[i] = 1.f; currency[i] = 1.f; }
    if (i < B_) dmin[i] = 0x7f7fffff;  // FLT_MAX bits
    if (i == 0) out[0] = 0.f;
  }
  const float* src = s ? labels : preds;
  unsigned short* dst = s ? pbbf : pabf;
  float* norms = s ? ln : pn;
  int w = tid >> 6, lane = tid & 63;
  size_t row0 = (size_t)blockIdx.x * 16 + (size_t)w * 4;
  float4 v[4];
  #pragma unroll
  for (int q = 0; q < 4; q++)
    v[q] = ((const float4*)(src + (row0 + q) * D_))[lane];
  __shared__ f4 part[4][64];
  __shared__ float nred[4];
  f4 s4;
  s4[0] = v[0].x + v[1].x + v[2].x + v[3].x;
  s4[1] = v[0].y + v[1].y + v[2].y + v[3].y;
  s4[2] = v[0].z + v[1].z + v[2].z + v[3].z;
  s4[3] = v[0].w + v[1].w + v[2].w + v[3].w;
  float nsum = 0.f;
  #pragma unroll
  for (int q = 0; q < 4; q++){
    float sum = v[q].x*v[q].x + v[q].y*v[q].y + v[q].z*v[q].z + v[q].w*v[q].w;
    #pragma unroll
    for (int off = 32; off >= 1; off >>= 1) sum += __shfl_xor(sum, off);
    if (lane == 0){ norms[row0 + q] = sum; nsum += sum; }
    ushort4 o; o.x = f2bf(v[q].x); o.y = f2bf(v[q].y); o.z = f2bf(v[q].z); o.w = f2bf(v[q].w);
    ((ushort4*)(dst + (row0 + q) * D_))[lane] = o;
  }
  part[w][lane] = s4;
  if (lane == 0) nred[w] = nsum;
  __syncthreads();
  if (tid < 64){
    f4 t = part[0][tid];
    #pragma unroll
    for (int q = 1; q < 4; q++){
      t[0] += part[q][tid][0]; t[1] += part[q][tid][1];
      t[2] += part[q][tid][2]; t[3] += part[q][tid][3];
    }
    *(f4*)(Ppart + ((size_t)s * 2048 + blockIdx.x) * 256 + tid * 4) = t;
  }
  if (tid == 0)
    npart[s * 2048 + blockIdx.x] = nred[0] + nred[1] + nred[2] + nred[3];
}

// d[b][n][m] = pn[n] + ln[m] - 2*dot via bf16 MFMA; NO stores — only per-batch min.
// ROUND-10 CHAMPION VERBATIM (43 us, ~800 TF = the m97-structure source-level
// plateau; r10 vs r12 measured both ends of the VGPR/occupancy trade):
// 256x256 tile, 512 threads, wave tile 128x64, BK=64, dbuf 128 KB,
// 128-B LDS rows + XOR r&7 (0 conflicts), batch->XCD pinning (FETCH == input
// size), pn/ln loaded AFTER the K-loop (pre-loop preload spills at 256-reg cap).
__global__ __launch_bounds__(512, 2) void gemm_minmax(
    const unsigned short* __restrict__ pa, const unsigned short* __restrict__ pbm,
    const float* __restrict__ pn, const float* __restrict__ ln,
    int* __restrict__ dmin)
{
  int lid = blockIdx.x;              // 1024 blocks, round-robin over 8 XCDs
  int l = lid >> 3;                  // 0..127 sequential per XCD
  int b = 2 * (lid & 7) + (l >> 6);  // 2 batches per XCD
  int t = l & 63;
  int tm = (t & 7) * 256, tn = (t >> 3) * 256;  // tm fastest: B-slice stays L2-hot
  const unsigned short* A  = pa  + (size_t)b * N_ * D_;
  const unsigned short* Bm = pbm + (size_t)b * N_ * D_;
  __shared__ __align__(16) unsigned short As[2][256 * 64];
  __shared__ __align__(16) unsigned short Bs[2][256 * 64];
  __shared__ float minred[8];
  int tid = threadIdx.x, lane = tid & 63, w = tid >> 6;
  int wm = (w >> 2) * 128, wn = (w & 3) * 64;
  int quad = lane >> 4, l15 = lane & 15;

  f4 acc[8][4];
  #pragma unroll
  for (int i = 0; i < 8; i++)
    #pragma unroll
    for (int j = 0; j < 4; j++) acc[i][j] = (f4)0.f;

  int lr = lane >> 3, ch = lane & 7;
  int gch = (ch ^ lr) * 8;           // XOR swizzle on the GLOBAL side (r&7 == lr)

  #pragma unroll
  for (int p = 0; p < 4; p++){
    int R = p * 64 + w * 8;
    int r = R + lr;
    __builtin_amdgcn_global_load_lds(
        (const AS1 unsigned int*)(const void*)&A[(size_t)(tm + r) * D_ + gch],
        (AS3 unsigned int*)(void*)&As[0][R * 64], 16, 0, 0);
    __builtin_amdgcn_global_load_lds(
        (const AS1 unsigned int*)(const void*)&Bm[(size_t)(tn + r) * D_ + gch],
        (AS3 unsigned int*)(void*)&Bs[0][R * 64], 16, 0, 0);
  }

  int buf = 0;
  for (int ki = 0; ki < 4; ki++){
    __syncthreads();   // drains buf's loads (issued one compute-phase ago)
    if (ki < 3){
      int kt = (ki + 1) * 64;
      #pragma unroll
      for (int p = 0; p < 4; p++){
        int R = p * 64 + w * 8;
        int r = R + lr;
        __builtin_amdgcn_global_load_lds(
            (const AS1 unsigned int*)(const void*)&A[(size_t)(tm + r) * D_ + kt + gch],
            (AS3 unsigned int*)(void*)&As[buf ^ 1][R * 64], 16, 0, 0);
        __builtin_amdgcn_global_load_lds(
            (const AS1 unsigned int*)(const void*)&Bm[(size_t)(tn + r) * D_ + kt + gch],
            (AS3 unsigned int*)(void*)&Bs[buf ^ 1][R * 64], 16, 0, 0);
      }
    }
    #pragma unroll
    for (int ks = 0; ks < 2; ks++){
      short8 af[8], bf[4];
      int j = ks * 4 + quad;
      #pragma unroll
      for (int i = 0; i < 8; i++){
        int ra = wm + i * 16 + l15;
        af[i] = *(const short8*)(&As[buf][ra * 64 + ((j ^ (ra & 7)) * 8)]);
      }
      #pragma unroll
      for (int jj = 0; jj < 4; jj++){
        int rb = wn + jj * 16 + l15;
        bf[jj] = *(const short8*)(&Bs[buf][rb * 64 + ((j ^ (rb & 7)) * 8)]);
      }
      #pragma unroll
      for (int i = 0; i < 8; i++)
        #pragma unroll
        for (int jj = 0; jj < 4; jj++)
          acc[i][jj] = __builtin_amdgcn_mfma_f32_16x16x32_bf16(af[i], bf[jj], acc[i][jj], 0, 0, 0);
    }
    buf ^= 1;
  }

  float4 pnr[8];
  float lnr[4];
  #pragma unroll
  for (int i = 0; i < 8; i++)
    pnr[i] = *(const float4*)&pn[(size_t)b * N_ + tm + wm + i * 16 + quad * 4];
  #pragma unroll
  for (int jj = 0; jj < 4; jj++)
    lnr[jj] = ln[(size_t)b * N_ + tn + wn + jj * 16 + l15];

  float mind = 3.4e38f;
  #pragma unroll
  for (int i = 0; i < 8; i++){
    float pv[4] = {pnr[i].x, pnr[i].y, pnr[i].z, pnr[i].w};
    #pragma unroll
    for (int jj = 0; jj < 4; jj++){
      #pragma unroll
      for (int reg = 0; reg < 4; reg++){
        float v = pv[reg] + lnr[jj] - 2.f * acc[i][jj][reg];
        mind = fminf(mind, v);
      }
    }
  }
  #pragma unroll
  for (int off = 32; off >= 1; off >>= 1) mind = fminf(mind, __shfl_xor(mind, off));
  if (lane == 0) minred[w] = mind;
  __syncthreads();
  if (tid == 0){
    float m = minred[0];
    #pragma unroll
    for (int q = 1; q < 8; q++) m = fminf(m, minred[q]);
    atomicMin(&dmin[b], __float_as_int(fmaxf(m, 0.f)));
  }
}

// Merged tail: (1) exact fallback for the 6 negative exp-factors (each skipped
// when provably negligible: B*N^2*dmax*e^{ef*dmin}/EPS < 1e-3 iff
// ef*(dmin-8) < -55; gating is monotone — if ef=-0.25 skips, all skip);
// (2) the ef=0 term. FAST PATH (all skipped -> cost == currency == 1 exactly):
// alpha = 1/2048 exactly, bw = 1, term = sum|p|^2 + sum|l|^2 - (sum p).(sum l)/1024
// from prep's fp32 partials. SLOW PATH (dead here): exact general computation.
__global__ __launch_bounds__(256) void tail(
    const unsigned short* __restrict__ pabf, const unsigned short* __restrict__ pbbf,
    const float* __restrict__ pn, const float* __restrict__ ln,
    float* __restrict__ cost, float* __restrict__ currency,
    const int* __restrict__ dmin, const float* __restrict__ Ppart,
    const float* __restrict__ npart, float* __restrict__ out)
{
  const float EF[6] = {-256.f, -64.f, -16.f, -4.f, -1.f, -0.25f};
  int b = blockIdx.x, tid = threadIdx.x;
  float dm = __int_as_float(dmin[b]);
  __shared__ float red[256];

  if (-0.25f * (dm - 8.f) < -55.f){
    // ---- fast path: all 6 negative iterations certified negligible ----
    float Pc = 0.f, Lc = 0.f;
    for (int k = 0; k < 128; k++){
      Pc += Ppart[((size_t)b * 128 + k) * 256 + tid];
      Lc += Ppart[((size_t)(2048 + b * 128 + k)) * 256 + tid];
    }
    float np = (tid < 128) ? npart[b * 128 + tid] : 0.f;
    float nl = (tid < 128) ? npart[2048 + b * 128 + tid] : 0.f;
    float Spn = blockReduceSum(np, red);
    float Sln = blockReduceSum(nl, red);
    float dot = blockReduceSum(Pc * Lc, red);
    if (tid == 0) atomicAdd(out, Spn + Sln - dot * (1.f / 1024.f));
    return;
  }

  // ---- slow exact path (not expected to execute for this input) ----
  __shared__ float alpha_l[N_];
  __shared__ float prow[D_];
  const unsigned short* A  = pabf + (size_t)b * N_ * D_;
  const unsigned short* Bm = pbbf + (size_t)b * N_ * D_;
  const float* pnb = pn + (size_t)b * N_;
  const float* lnb = ln + (size_t)b * N_;
  float* costb = cost + (size_t)b * N_;
  float* curb  = currency + (size_t)b * N_;
  for (int it = 0; it < 6; it++){
    float ef = EF[it];
    if (ef * (dm - 8.f) < -55.f) continue;
    float cost_c[8], colsum_c[8], bw_c[8], costnew_c[8];
    #pragma unroll
    for (int j = 0; j < 8; j++){ cost_c[j] = costb[j*256+tid]; colsum_c[j] = 0.f; }
    for (int r = 0; r < N_; r++){
      prow[tid] = bf2f(A[(size_t)r * D_ + tid]);
      __syncthreads();
      float s_c[8], rs = 0.f;
      for (int j = 0; j < 8; j++){
        int m = j*256+tid; float dot = 0.f;
        for (int k = 0; k < D_; k++) dot += prow[k] * bf2f(Bm[(size_t)m * D_ + k]);
        float d = pnb[r] + lnb[m] - 2.f*dot;
        float s = __expf(ef * d) * cost_c[j];
        s_c[j] = s; rs += s;
      }
      float tot = blockReduceSum(rs, red);
      float a = curb[r] / (tot + EPS_);
      if (tid == 0) alpha_l[r] = a;
      #pragma unroll
      for (int j = 0; j < 8; j++) colsum_c[j] += s_c[j] * a;
      __syncthreads();
    }
    #pragma unroll
    for (int j = 0; j < 8; j++){
      float cs = colsum_c[j];
      float bw = fminf(cost_c[j] / (cs + EPS_), 1.f);
      bw_c[j] = bw; costnew_c[j] = fmaxf(cost_c[j] - bw*cs, 0.f);
    }
    float contrib = 0.f;
    for (int r = 0; r < N_; r++){
      prow[tid] = bf2f(A[(size_t)r * D_ + tid]);
      __syncthreads();
      float a = alpha_l[r], rbs = 0.f;
      for (int j = 0; j < 8; j++){
        int m = j*256+tid; float dot = 0.f;
        for (int k = 0; k < D_; k++) dot += prow[k] * bf2f(Bm[(size_t)m * D_ + k]);
        float d = pnb[r] + lnb[m] - 2.f*dot;
        float bid = __expf(ef * d) * cost_c[j] * a * bw_c[j];
        rbs += bid; contrib += bid * d;
      }
      float tot = blockReduceSum(rbs, red);
      if (tid == 0) curb[r] = fmaxf(curb[r] - tot, 0.f);
      __syncthreads();
    }
    #pragma unroll
    for (int j = 0; j < 8; j++) costb[j*256+tid] = costnew_c[j];
    float ctot = blockReduceSum(contrib, red);
    if (tid == 0) atomicAdd(out, ctot);
    __syncthreads();
  }
  // ef=0 closed form with the general state (exact):
  float s = 0.f;
  #pragma unroll
  for (int j = 0; j < 8; j++) s += costb[j*256+tid];
  float Sc = blockReduceSum(s, red);
  float sa = 0.f, spn = 0.f;
  #pragma unroll
  for (int j = 0; j < 8; j++){
    int i = j*256+tid;
    float a = curb[i] / (Sc + EPS_);
    alpha_l[i] = a; sa += a; spn += a * pnb[i];
  }
  float Sa  = blockReduceSum(sa, red);
  float Spn = blockReduceSum(spn, red);
  float Pc = 0.f;
  for (int r = 0; r < N_; r++)
    Pc += alpha_l[r] * bf2f(A[(size_t)r * D_ + tid]);
  __syncthreads();
  float sv = 0.f, sln = 0.f;
  #pragma unroll
  for (int j = 0; j < 8; j++){
    int i = j*256+tid;
    float c = costb[i];
    float bw = fminf(c / (c * Sa + EPS_), 1.f);
    float vv = c * bw;
    alpha_l[i] = vv; sv += vv; sln += vv * lnb[i];
  }
  float Sv  = blockReduceSum(sv, red);
  float Sln = blockReduceSum(sln, red);
  float Lc = 0.f;
  for (int m = 0; m < N_; m++)
    Lc += alpha_l[m] * bf2f(Bm[(size_t)m * D_ + tid]);
  float dot = blockReduceSum(Pc * Lc, red);
  if (tid == 0) atomicAdd(out, Spn * Sv + Sa * Sln - 2.f * dot);
}

extern "C" void kernel_launch(void* const* d_in, const int* in_sizes, int n_in,
                              void* d_out, int out_size, void* d_ws, size_t ws_size,
                              hipStream_t stream)
{
  const float* preds  = (const float*)d_in[0];
  const float* labels = (const float*)d_in[1];
  float* out = (float*)d_out;
  char* ws = (char*)d_ws;
  const size_t BN = (size_t)B_ * N_;
  size_t off = 0;
  float* cost     = (float*)(ws + off); off += BN * 4;
  float* currency = (float*)(ws + off); off += BN * 4;
  float* pn       = (float*)(ws + off); off += BN * 4;
  float* ln       = (float*)(ws + off); off += BN * 4;
  int*   dmin     = (int*)(ws + off);   off += 256;
  float* npart    = (float*)(ws + off); off += (size_t)2 * 2048 * 4;
  float* Ppart    = (float*)(ws + off); off += (size_t)2 * 2048 * 256 * 4;
  unsigned short* pabf = (unsigned short*)(ws + off); off += BN * D_ * 2;
  unsigned short* pbbf = (unsigned short*)(ws + off); off += BN * D_ * 2;

  prep_kernel<<<dim3((unsigned)(BN / 16), 2), 256, 0, stream>>>(
      preds, labels, pabf, pbbf, pn, ln, cost, currency, dmin, Ppart, npart, out);
  gemm_minmax<<<dim3(1024), 512, 0, stream>>>(pabf, pbbf, pn, ln, dmin);
  tail<<<dim3(B_), 256, 0, stream>>>(pabf, pbbf, pn, ln, cost, currency, dmin,
                                     Ppart, npart, out);
}

// Round 15
// 142.056 us; speedup vs baseline: 1.1056x; 1.0322x over previous
//
#include <hip/hip_runtime.h>
#include <cstdint>

#define B_ 16
#define N_ 2048
#define D_ 256
#define EPS_ 1e-9f

#define AS1 __attribute__((address_space(1)))
#define AS3 __attribute__((address_space(3)))

typedef float f4 __attribute__((ext_vector_type(4)));

__device__ float blockReduceSum(float x, float* red){
  int tid = threadIdx.x;
  red[tid] = x; __syncthreads();
  #pragma unroll
  for (int off = 128; off > 0; off >>= 1){
    if (tid < off) red[tid] += red[tid + off];
    __syncthreads();
  }
  float r = red[0]; __syncthreads();
  return r;
}

// fp32 norm + fp8(e4m3) conversion; 4 rows/wave, 16 rows/block (one batch/block).
// Emits race-free per-block partials Ppart/npart for tail's fast path.
// Also inits cost/currency/dmin/out (no separate memset dispatch).
__global__ __launch_bounds__(256) void prep_kernel(
    const float* __restrict__ preds, const float* __restrict__ labels,
    unsigned char* __restrict__ pa8, unsigned char* __restrict__ pb8,
    float* __restrict__ pn, float* __restrict__ ln,
    float* __restrict__ cost, float* __restrict__ currency,
    int* __restrict__ dmin, float* __restrict__ Ppart,
    float* __restrict__ npart, float* __restrict__ out){
  int s = blockIdx.y;
  int tid = threadIdx.x;
  if (s == 0){
    int i = blockIdx.x * 256 + tid;
    if (i < B_ * N_){ cost[i] = 1.f; currency[i] = 1.f; }
    if (i < B_) dmin[i] = 0x7f7fffff;  // FLT_MAX bits
    if (i == 0) out[0] = 0.f;
  }
  const float* src = s ? labels : preds;
  unsigned char* dst = s ? pb8 : pa8;
  float* norms = s ? ln : pn;
  int w = tid >> 6, lane = tid & 63;
  size_t row0 = (size_t)blockIdx.x * 16 + (size_t)w * 4;
  float4 v[4];
  #pragma unroll
  for (int q = 0; q < 4; q++)
    v[q] = ((const float4*)(src + (row0 + q) * D_))[lane];
  __shared__ f4 part[4][64];
  __shared__ float nred[4];
  f4 s4;
  s4[0] = v[0].x + v[1].x + v[2].x + v[3].x;
  s4[1] = v[0].y + v[1].y + v[2].y + v[3].y;
  s4[2] = v[0].z + v[1].z + v[2].z + v[3].z;
  s4[3] = v[0].w + v[1].w + v[2].w + v[3].w;
  float nsum = 0.f;
  #pragma unroll
  for (int q = 0; q < 4; q++){
    float sum = v[q].x*v[q].x + v[q].y*v[q].y + v[q].z*v[q].z + v[q].w*v[q].w;
    #pragma unroll
    for (int off = 32; off >= 1; off >>= 1) sum += __shfl_xor(sum, off);
    if (lane == 0){ norms[row0 + q] = sum; nsum += sum; }
    int pk = 0;
    pk = __builtin_amdgcn_cvt_pk_fp8_f32(v[q].x, v[q].y, pk, false); // bytes 0,1
    pk = __builtin_amdgcn_cvt_pk_fp8_f32(v[q].z, v[q].w, pk, true);  // bytes 2,3
    ((unsigned int*)(dst + (row0 + q) * D_))[lane] = (unsigned int)pk;
  }
  part[w][lane] = s4;
  if (lane == 0) nred[w] = nsum;
  __syncthreads();
  if (tid < 64){
    f4 t = part[0][tid];
    #pragma unroll
    for (int q = 1; q < 4; q++){
      t[0] += part[q][tid][0]; t[1] += part[q][tid][1];
      t[2] += part[q][tid][2]; t[3] += part[q][tid][3];
    }
    *(f4*)(Ppart + ((size_t)s * 2048 + blockIdx.x) * 256 + tid * 4) = t;
  }
  if (tid == 0)
    npart[s * 2048 + blockIdx.x] = nred[0] + nred[1] + nred[2] + nred[3];
}

// d[b][n][m] = pn[n] + ln[m] - 2*dot via FP8 MFMA; NO stores — only per-batch min.
// fp8 e4m3 port of the round-10 champion (ladder step 3-fp8): 256x256 tile,
// 512 threads, wave tile 128x64, BK=128 -> rows stay 128 BYTES so the proven
// conflict-free staging geometry (XOR r&7 on 16-B chunks, global-side swizzle)
// is byte-identical. Staging + LDS bytes HALVE vs bf16; MFMA count unchanged
// (fp8 16x16x32 = bf16 rate); fragments are ds_read_b64 (logical byte
// k = s*32 + quad*8 -> chunk 2s+(quad>>1), sub (quad&1)*8). dmin feeds only
// the skip certificate (guard widened 8->16 for fp8 quantization error).
__global__ __launch_bounds__(512, 2) void gemm_minmax(
    const unsigned char* __restrict__ pa, const unsigned char* __restrict__ pbm,
    const float* __restrict__ pn, const float* __restrict__ ln,
    int* __restrict__ dmin)
{
  int lid = blockIdx.x;              // 1024 blocks, round-robin over 8 XCDs
  int l = lid >> 3;                  // 0..127 sequential per XCD
  int b = 2 * (lid & 7) + (l >> 6);  // 2 batches per XCD
  int t = l & 63;
  int tm = (t & 7) * 256, tn = (t >> 3) * 256;  // tm fastest: B-slice stays L2-hot
  const unsigned char* A  = pa  + (size_t)b * N_ * D_;
  const unsigned char* Bm = pbm + (size_t)b * N_ * D_;
  __shared__ __align__(16) unsigned char As[2][256 * 128];
  __shared__ __align__(16) unsigned char Bs[2][256 * 128];
  __shared__ float minred[8];
  int tid = threadIdx.x, lane = tid & 63, w = tid >> 6;
  int wm = (w >> 2) * 128, wn = (w & 3) * 64;
  int quad = lane >> 4, l15 = lane & 15;

  f4 acc[8][4];
  #pragma unroll
  for (int i = 0; i < 8; i++)
    #pragma unroll
    for (int j = 0; j < 4; j++) acc[i][j] = (f4)0.f;

  int lr = lane >> 3, ch = lane & 7;
  int gch = (ch ^ lr) * 16;          // byte offset; XOR swizzle on the GLOBAL side

  // prefetch k-chunk 0 into buffer 0 (rows are 128 B: 8 rows per wave-issue)
  #pragma unroll
  for (int p = 0; p < 4; p++){
    int R = p * 64 + w * 8;
    int r = R + lr;
    __builtin_amdgcn_global_load_lds(
        (const AS1 unsigned int*)(const void*)&A[(size_t)(tm + r) * D_ + gch],
        (AS3 unsigned int*)(void*)&As[0][R * 128], 16, 0, 0);
    __builtin_amdgcn_global_load_lds(
        (const AS1 unsigned int*)(const void*)&Bm[(size_t)(tn + r) * D_ + gch],
        (AS3 unsigned int*)(void*)&Bs[0][R * 128], 16, 0, 0);
  }

  int buf = 0;
  for (int ki = 0; ki < 2; ki++){
    __syncthreads();   // drains buf's loads (issued one compute-phase ago)
    if (ki < 1){
      int kt = 128;
      #pragma unroll
      for (int p = 0; p < 4; p++){
        int R = p * 64 + w * 8;
        int r = R + lr;
        __builtin_amdgcn_global_load_lds(
            (const AS1 unsigned int*)(const void*)&A[(size_t)(tm + r) * D_ + kt + gch],
            (AS3 unsigned int*)(void*)&As[buf ^ 1][R * 128], 16, 0, 0);
        __builtin_amdgcn_global_load_lds(
            (const AS1 unsigned int*)(const void*)&Bm[(size_t)(tn + r) * D_ + kt + gch],
            (AS3 unsigned int*)(void*)&Bs[buf ^ 1][R * 128], 16, 0, 0);
      }
    }
    #pragma unroll
    for (int s = 0; s < 4; s++){
      long af[8], bf[4];
      int base = s * 2 + (quad >> 1);     // logical 16-B chunk of k = s*32+quad*8
      int sub = (quad & 1) * 8;
      #pragma unroll
      for (int i = 0; i < 8; i++){
        int ra = wm + i * 16 + l15;
        af[i] = *(const long*)(&As[buf][ra * 128 + ((base ^ (ra & 7)) * 16) + sub]);
      }
      #pragma unroll
      for (int jj = 0; jj < 4; jj++){
        int rb = wn + jj * 16 + l15;
        bf[jj] = *(const long*)(&Bs[buf][rb * 128 + ((base ^ (rb & 7)) * 16) + sub]);
      }
      #pragma unroll
      for (int i = 0; i < 8; i++)
        #pragma unroll
        for (int jj = 0; jj < 4; jj++)
          acc[i][jj] = __builtin_amdgcn_mfma_f32_16x16x32_fp8_fp8(af[i], bf[jj], acc[i][jj], 0, 0, 0);
    }
    buf ^= 1;
  }

  // epilogue: pn/ln loaded AFTER the K-loop (pre-loop preload = r9 spill bomb).
  // C/D layout col = lane&15, row = quad*4 + reg (dtype-independent, verified).
  float4 pnr[8];
  float lnr[4];
  #pragma unroll
  for (int i = 0; i < 8; i++)
    pnr[i] = *(const float4*)&pn[(size_t)b * N_ + tm + wm + i * 16 + quad * 4];
  #pragma unroll
  for (int jj = 0; jj < 4; jj++)
    lnr[jj] = ln[(size_t)b * N_ + tn + wn + jj * 16 + l15];

  float mind = 3.4e38f;
  #pragma unroll
  for (int i = 0; i < 8; i++){
    float pv[4] = {pnr[i].x, pnr[i].y, pnr[i].z, pnr[i].w};
    #pragma unroll
    for (int jj = 0; jj < 4; jj++){
      #pragma unroll
      for (int reg = 0; reg < 4; reg++){
        float v = pv[reg] + lnr[jj] - 2.f * acc[i][jj][reg];
        mind = fminf(mind, v);
      }
    }
  }
  #pragma unroll
  for (int off = 32; off >= 1; off >>= 1) mind = fminf(mind, __shfl_xor(mind, off));
  if (lane == 0) minred[w] = mind;
  __syncthreads();
  if (tid == 0){
    float m = minred[0];
    #pragma unroll
    for (int q = 1; q < 8; q++) m = fminf(m, minred[q]);
    atomicMin(&dmin[b], __float_as_int(fmaxf(m, 0.f)));
  }
}

// Merged tail: (1) exact fallback for the 6 negative exp-factors (each skipped
// when provably negligible: B*N^2*dmax*e^{ef*dmin}/EPS < 1e-3 iff
// ef*(dmin-16) < -55; guard 16 covers fp8 dot quantization error, |err|<~8
// at 5-sigma over 4M pairs; gating monotone — if ef=-0.25 skips, all skip);
// (2) the ef=0 term. FAST PATH (all skipped -> cost == currency == 1 exactly):
// alpha = 1/2048 exactly, bw = 1, term = sum|p|^2 + sum|l|^2 - (sum p).(sum l)/1024
// from prep's fp32 partials. SLOW PATH (dead here): exact from fp32 originals.
__global__ __launch_bounds__(256) void tail(
    const float* __restrict__ preds, const float* __restrict__ labels,
    const float* __restrict__ pn, const float* __restrict__ ln,
    float* __restrict__ cost, float* __restrict__ currency,
    const int* __restrict__ dmin, const float* __restrict__ Ppart,
    const float* __restrict__ npart, float* __restrict__ out)
{
  const float EF[6] = {-256.f, -64.f, -16.f, -4.f, -1.f, -0.25f};
  int b = blockIdx.x, tid = threadIdx.x;
  float dm = __int_as_float(dmin[b]);
  __shared__ float red[256];

  if (-0.25f * (dm - 16.f) < -55.f){
    // ---- fast path: all 6 negative iterations certified negligible ----
    float Pc = 0.f, Lc = 0.f;
    for (int k = 0; k < 128; k++){
      Pc += Ppart[((size_t)b * 128 + k) * 256 + tid];
      Lc += Ppart[((size_t)(2048 + b * 128 + k)) * 256 + tid];
    }
    float np = (tid < 128) ? npart[b * 128 + tid] : 0.f;
    float nl = (tid < 128) ? npart[2048 + b * 128 + tid] : 0.f;
    float Spn = blockReduceSum(np, red);
    float Sln = blockReduceSum(nl, red);
    float dot = blockReduceSum(Pc * Lc, red);
    if (tid == 0) atomicAdd(out, Spn + Sln - dot * (1.f / 1024.f));
    return;
  }

  // ---- slow exact path from fp32 originals (not expected to execute) ----
  __shared__ float alpha_l[N_];
  __shared__ float prow[D_];
  const float* A  = preds  + (size_t)b * N_ * D_;
  const float* Bm = labels + (size_t)b * N_ * D_;
  const float* pnb = pn + (size_t)b * N_;
  const float* lnb = ln + (size_t)b * N_;
  float* costb = cost + (size_t)b * N_;
  float* curb  = currency + (size_t)b * N_;
  for (int it = 0; it < 6; it++){
    float ef = EF[it];
    if (ef * (dm - 16.f) < -55.f) continue;
    float cost_c[8], colsum_c[8], bw_c[8], costnew_c[8];
    #pragma unroll
    for (int j = 0; j < 8; j++){ cost_c[j] = costb[j*256+tid]; colsum_c[j] = 0.f; }
    for (int r = 0; r < N_; r++){
      prow[tid] = A[(size_t)r * D_ + tid];
      __syncthreads();
      float s_c[8], rs = 0.f;
      for (int j = 0; j < 8; j++){
        int m = j*256+tid; float dot = 0.f;
        for (int k = 0; k < D_; k++) dot += prow[k] * Bm[(size_t)m * D_ + k];
        float d = pnb[r] + lnb[m] - 2.f*dot;
        float s = __expf(ef * d) * cost_c[j];
        s_c[j] = s; rs += s;
      }
      float tot = blockReduceSum(rs, red);
      float a = curb[r] / (tot + EPS_);
      if (tid == 0) alpha_l[r] = a;
      #pragma unroll
      for (int j = 0; j < 8; j++) colsum_c[j] += s_c[j] * a;
      __syncthreads();
    }
    #pragma unroll
    for (int j = 0; j < 8; j++){
      float cs = colsum_c[j];
      float bw = fminf(cost_c[j] / (cs + EPS_), 1.f);
      bw_c[j] = bw; costnew_c[j] = fmaxf(cost_c[j] - bw*cs, 0.f);
    }
    float contrib = 0.f;
    for (int r = 0; r < N_; r++){
      prow[tid] = A[(size_t)r * D_ + tid];
      __syncthreads();
      float a = alpha_l[r], rbs = 0.f;
      for (int j = 0; j < 8; j++){
        int m = j*256+tid; float dot = 0.f;
        for (int k = 0; k < D_; k++) dot += prow[k] * Bm[(size_t)m * D_ + k];
        float d = pnb[r] + lnb[m] - 2.f*dot;
        float bid = __expf(ef * d) * cost_c[j] * a * bw_c[j];
        rbs += bid; contrib += bid * d;
      }
      float tot = blockReduceSum(rbs, red);
      if (tid == 0) curb[r] = fmaxf(curb[r] - tot, 0.f);
      __syncthreads();
    }
    #pragma unroll
    for (int j = 0; j < 8; j++) costb[j*256+tid] = costnew_c[j];
    float ctot = blockReduceSum(contrib, red);
    if (tid == 0) atomicAdd(out, ctot);
    __syncthreads();
  }
  // ef=0 closed form with the general state (exact):
  float s = 0.f;
  #pragma unroll
  for (int j = 0; j < 8; j++) s += costb[j*256+tid];
  float Sc = blockReduceSum(s, red);
  float sa = 0.f, spn = 0.f;
  #pragma unroll
  for (int j = 0; j < 8; j++){
    int i = j*256+tid;
    float a = curb[i] / (Sc + EPS_);
    alpha_l[i] = a; sa += a; spn += a * pnb[i];
  }
  float Sa  = blockReduceSum(sa, red);
  float Spn = blockReduceSum(spn, red);
  float Pc = 0.f;
  for (int r = 0; r < N_; r++)
    Pc += alpha_l[r] * A[(size_t)r * D_ + tid];
  __syncthreads();
  float sv = 0.f, sln = 0.f;
  #pragma unroll
  for (int j = 0; j < 8; j++){
    int i = j*256+tid;
    float c = costb[i];
    float bw = fminf(c / (c * Sa + EPS_), 1.f);
    float vv = c * bw;
    alpha_l[i] = vv; sv += vv; sln += vv * lnb[i];
  }
  float Sv  = blockReduceSum(sv, red);
  float Sln = blockReduceSum(sln, red);
  float Lc = 0.f;
  for (int m = 0; m < N_; m++)
    Lc += alpha_l[m] * Bm[(size_t)m * D_ + tid];
  float dot = blockReduceSum(Pc * Lc, red);
  if (tid == 0) atomicAdd(out, Spn * Sv + Sa * Sln - 2.f * dot);
}

extern "C" void kernel_launch(void* const* d_in, const int* in_sizes, int n_in,
                              void* d_out, int out_size, void* d_ws, size_t ws_size,
                              hipStream_t stream)
{
  const float* preds  = (const float*)d_in[0];
  const float* labels = (const float*)d_in[1];
  float* out = (float*)d_out;
  char* ws = (char*)d_ws;
  const size_t BN = (size_t)B_ * N_;
  size_t off = 0;
  float* cost     = (float*)(ws + off); off += BN * 4;
  float* currency = (float*)(ws + off); off += BN * 4;
  float* pn       = (float*)(ws + off); off += BN * 4;
  float* ln       = (float*)(ws + off); off += BN * 4;
  int*   dmin     = (int*)(ws + off);   off += 256;
  float* npart    = (float*)(ws + off); off += (size_t)2 * 2048 * 4;
  float* Ppart    = (float*)(ws + off); off += (size_t)2 * 2048 * 256 * 4;
  unsigned char* pa8 = (unsigned char*)(ws + off); off += BN * D_;
  unsigned char* pb8 = (unsigned char*)(ws + off); off += BN * D_;

  prep_kernel<<<dim3((unsigned)(BN / 16), 2), 256, 0, stream>>>(
      preds, labels, pa8, pb8, pn, ln, cost, currency, dmin, Ppart, npart, out);
  gemm_minmax<<<dim3(1024), 512, 0, stream>>>(pa8, pb8, pn, ln, dmin);
  tail<<<dim3(B_), 256, 0, stream>>>(preds, labels, pn, ln, cost, currency, dmin,
                                     Ppart, npart, out);
}